// Round 5
// baseline (1432.237 us; speedup 1.0000x reference)
//
#include <hip/hip_runtime.h>

#define K_DIM 256
__device__ __forceinline__ float lrelu_f(float x) { return x >= 0.f ? x : 0.2f * x; }

// ---------------- graph prep kernels ----------------

__global__ __launch_bounds__(256) void hist_kernel(const int* __restrict__ dst,
                                                   int* __restrict__ cnt, int E) {
  int e = blockIdx.x * 256 + threadIdx.x;
  if (e < E) atomicAdd(&cnt[dst[e]], 1);
}

__global__ __launch_bounds__(256) void dinv_kernel(const int* __restrict__ cnt,
                                                   float* __restrict__ dinv, int n) {
  int i = blockIdx.x * 256 + threadIdx.x;
  if (i < n) dinv[i] = rsqrtf((float)cnt[i] + 1.0f);
}

__global__ __launch_bounds__(256) void scan1_kernel(const int* __restrict__ cnt,
                                                    int* __restrict__ incl,
                                                    int* __restrict__ bsum, int n) {
  __shared__ int sm[256];
  int t = threadIdx.x;
  int i = blockIdx.x * 256 + t;
  int v = (i < n) ? cnt[i] : 0;
  sm[t] = v;
  __syncthreads();
  for (int off = 1; off < 256; off <<= 1) {
    int u = (t >= off) ? sm[t - off] : 0;
    __syncthreads();
    sm[t] += u;
    __syncthreads();
  }
  if (i < n) incl[i] = sm[t];
  if (t == 255) bsum[blockIdx.x] = sm[255];
}

__global__ __launch_bounds__(256) void scan2_kernel(const int* __restrict__ bsum,
                                                    int* __restrict__ boff, int nb) {
  __shared__ int sm[256];
  int t = threadIdx.x;
  int v = (t < nb) ? bsum[t] : 0;
  sm[t] = v;
  __syncthreads();
  for (int off = 1; off < 256; off <<= 1) {
    int u = (t >= off) ? sm[t - off] : 0;
    __syncthreads();
    sm[t] += u;
    __syncthreads();
  }
  boff[t] = sm[t] - v;  // exclusive
}

__global__ __launch_bounds__(256) void scan3_kernel(const int* __restrict__ incl,
                                                    const int* __restrict__ boff,
                                                    int* __restrict__ rowptr, int n) {
  int i = blockIdx.x * 256 + threadIdx.x;
  if (i < n) rowptr[i + 1] = incl[i] + boff[blockIdx.x];
  if (i == 0) rowptr[0] = 0;
}

__global__ __launch_bounds__(256) void scatter_kernel(const int* __restrict__ src,
                                                      const int* __restrict__ dst,
                                                      const int* __restrict__ rowptr,
                                                      int* __restrict__ cursor,
                                                      const float* __restrict__ dinv,
                                                      int* __restrict__ esrc,
                                                      float* __restrict__ ew, int E) {
  int e = blockIdx.x * 256 + threadIdx.x;
  if (e < E) {
    int d = dst[e];
    int p = rowptr[d] + atomicAdd(&cursor[d], 1);
    int s = src[e];
    esrc[p] = s;
    ew[p] = dinv[s];
  }
}

// ---------------- GEMM: H[M,NCOLS] = act(A[M,256]) @ W[NCOLS,256]^T ----------------
// 128x128 tile, 256 threads, 8x8 microtile (as 2x2 blocks of 4x4), BK=16.

template <bool LRELU, int NCOLS>
__global__ __launch_bounds__(256) void gemm_kernel(const float* __restrict__ A,
                                                   const float* __restrict__ W,
                                                   float* __restrict__ H, int M) {
  constexpr int BK = 16;
  __shared__ float As[BK][128];
  __shared__ float Ws[BK][128];
  const int bm = blockIdx.x * 128;
  const int bn = blockIdx.y * 128;
  const int tid = threadIdx.x;
  const int tx = tid & 15;   // N dir
  const int ty = tid >> 4;   // M dir
  const int lr = tid >> 2;   // staging row 0..63
  const int lk = (tid & 3) << 2;  // staging k quad

  float acc[2][2][4][4];
#pragma unroll
  for (int a = 0; a < 2; a++)
#pragma unroll
    for (int b = 0; b < 2; b++)
#pragma unroll
      for (int i = 0; i < 4; i++)
#pragma unroll
        for (int j = 0; j < 4; j++) acc[a][b][i][j] = 0.f;

  for (int k0 = 0; k0 < K_DIM; k0 += BK) {
#pragma unroll
    for (int h = 0; h < 2; ++h) {
      int row = bm + h * 64 + lr;
      int rc = row < M ? row : M - 1;
      float4 v = *(const float4*)(A + (size_t)rc * K_DIM + k0 + lk);
      if (LRELU) {
        v.x = lrelu_f(v.x); v.y = lrelu_f(v.y); v.z = lrelu_f(v.z); v.w = lrelu_f(v.w);
      }
      As[lk + 0][h * 64 + lr] = v.x;
      As[lk + 1][h * 64 + lr] = v.y;
      As[lk + 2][h * 64 + lr] = v.z;
      As[lk + 3][h * 64 + lr] = v.w;
    }
#pragma unroll
    for (int h = 0; h < 2; ++h) {
      int row = bn + h * 64 + lr;
      float4 v = *(const float4*)(W + (size_t)row * K_DIM + k0 + lk);
      Ws[lk + 0][h * 64 + lr] = v.x;
      Ws[lk + 1][h * 64 + lr] = v.y;
      Ws[lk + 2][h * 64 + lr] = v.z;
      Ws[lk + 3][h * 64 + lr] = v.w;
    }
    __syncthreads();
#pragma unroll
    for (int kk = 0; kk < BK; ++kk) {
      float4 va0 = *(const float4*)&As[kk][ty * 4];
      float4 va1 = *(const float4*)&As[kk][64 + ty * 4];
      float4 vb0 = *(const float4*)&Ws[kk][tx * 4];
      float4 vb1 = *(const float4*)&Ws[kk][64 + tx * 4];
      float a0[4] = {va0.x, va0.y, va0.z, va0.w};
      float a1[4] = {va1.x, va1.y, va1.z, va1.w};
      float b0[4] = {vb0.x, vb0.y, vb0.z, vb0.w};
      float b1[4] = {vb1.x, vb1.y, vb1.z, vb1.w};
#pragma unroll
      for (int i = 0; i < 4; i++)
#pragma unroll
        for (int j = 0; j < 4; j++) {
          acc[0][0][i][j] = fmaf(a0[i], b0[j], acc[0][0][i][j]);
          acc[0][1][i][j] = fmaf(a0[i], b1[j], acc[0][1][i][j]);
          acc[1][0][i][j] = fmaf(a1[i], b0[j], acc[1][0][i][j]);
          acc[1][1][i][j] = fmaf(a1[i], b1[j], acc[1][1][i][j]);
        }
    }
    __syncthreads();
  }

#pragma unroll
  for (int mh = 0; mh < 2; ++mh)
#pragma unroll
    for (int i = 0; i < 4; i++) {
      int row = bm + mh * 64 + ty * 4 + i;
      if (row < M) {
#pragma unroll
        for (int nh = 0; nh < 2; ++nh) {
          float4 o;
          o.x = acc[mh][nh][i][0];
          o.y = acc[mh][nh][i][1];
          o.z = acc[mh][nh][i][2];
          o.w = acc[mh][nh][i][3];
          *(float4*)(H + (size_t)row * NCOLS + bn + nh * 64 + tx * 4) = o;
        }
      }
    }
}

// ---------------- fused: At = lrelu(aggregate_L(H) + b_L); Hn = At @ W_{L+1}^T ----------------
// Block = 256 threads = 4 waves, 32 nodes. Phase A: each wave gathers 8 nodes
// (4-way edge batching) into LDS At[32][260] (pad 260: bank-safe, fp32 float4-aligned).
// Phase B: 32xNOUT GEMM, K=256 in BK=16 chunks, W chunk staged transposed in LDS.
// LDS = 33.3KB + 16KB -> 3 blocks/CU so gather waves of one block overlap GEMM waves
// of another (GEMM VALU hides under gather memory stalls).

template <int NOUT>
__global__ __launch_bounds__(256) void fused_agg_gemm(
    const float* __restrict__ H, const int* __restrict__ rowptr,
    const int* __restrict__ esrc, const float* __restrict__ ew,
    const float* __restrict__ dinv, const float* __restrict__ bias,
    const float* __restrict__ W, float* __restrict__ Hn, int n) {
  __shared__ float At[32][260];
  __shared__ float Ws[16][NOUT];
  const int tid = threadIdx.x;
  const int lane = tid & 63;
  const int wv = tid >> 6;
  const int blk = blockIdx.x * 32;

  // ---- phase A: aggregate + bias + lrelu -> At ----
#pragma unroll
  for (int i = 0; i < 8; ++i) {
    const int m = wv * 8 + i;
    const int node = blk + m;
    if (node < n) {
      const float di = dinv[node];
      float4 hs = *(const float4*)(H + (size_t)node * 256 + lane * 4);
      float acc0 = di * hs.x, acc1 = di * hs.y, acc2 = di * hs.z, acc3 = di * hs.w;
      const int e1 = rowptr[node + 1];
      int e = rowptr[node];
      for (; e + 4 <= e1; e += 4) {
        int s0 = esrc[e + 0], s1 = esrc[e + 1], s2 = esrc[e + 2], s3 = esrc[e + 3];
        float w0 = ew[e + 0], w1 = ew[e + 1], w2 = ew[e + 2], w3 = ew[e + 3];
        float4 h0 = *(const float4*)(H + (size_t)s0 * 256 + lane * 4);
        float4 h1 = *(const float4*)(H + (size_t)s1 * 256 + lane * 4);
        float4 h2 = *(const float4*)(H + (size_t)s2 * 256 + lane * 4);
        float4 h3 = *(const float4*)(H + (size_t)s3 * 256 + lane * 4);
        acc0 = fmaf(w3, h3.x, fmaf(w2, h2.x, fmaf(w1, h1.x, fmaf(w0, h0.x, acc0))));
        acc1 = fmaf(w3, h3.y, fmaf(w2, h2.y, fmaf(w1, h1.y, fmaf(w0, h0.y, acc1))));
        acc2 = fmaf(w3, h3.z, fmaf(w2, h2.z, fmaf(w1, h1.z, fmaf(w0, h0.z, acc2))));
        acc3 = fmaf(w3, h3.w, fmaf(w2, h2.w, fmaf(w1, h1.w, fmaf(w0, h0.w, acc3))));
      }
      for (; e < e1; ++e) {
        int s = esrc[e];
        float w = ew[e];
        float4 h = *(const float4*)(H + (size_t)s * 256 + lane * 4);
        acc0 = fmaf(w, h.x, acc0);
        acc1 = fmaf(w, h.y, acc1);
        acc2 = fmaf(w, h.z, acc2);
        acc3 = fmaf(w, h.w, acc3);
      }
      float4 b = *(const float4*)(bias + lane * 4);
      float4 o;
      o.x = lrelu_f(fmaf(di, acc0, b.x));
      o.y = lrelu_f(fmaf(di, acc1, b.y));
      o.z = lrelu_f(fmaf(di, acc2, b.z));
      o.w = lrelu_f(fmaf(di, acc3, b.w));
      *(float4*)&At[m][lane * 4] = o;
    }
  }
  __syncthreads();

  // ---- phase B: Hn[blk..blk+31][:] = At @ W^T ----
  const int tx = tid & 31;   // col group
  const int ty = tid >> 5;   // row group 0..7
  float accA[4][4];
  float accB[4][4];
#pragma unroll
  for (int i = 0; i < 4; ++i)
#pragma unroll
    for (int j = 0; j < 4; ++j) {
      accA[i][j] = 0.f;
      if (NOUT == 256) accB[i][j] = 0.f;
    }

  for (int k0 = 0; k0 < 256; k0 += 16) {
    if (tid < NOUT) {
      const float* wr = W + (size_t)tid * 256 + k0;
#pragma unroll
      for (int q = 0; q < 4; ++q) {
        float4 v = *(const float4*)(wr + 4 * q);
        Ws[4 * q + 0][tid] = v.x;
        Ws[4 * q + 1][tid] = v.y;
        Ws[4 * q + 2][tid] = v.z;
        Ws[4 * q + 3][tid] = v.w;
      }
    }
    __syncthreads();
#pragma unroll
    for (int kk = 0; kk < 16; ++kk) {
      float a[4];
#pragma unroll
      for (int i = 0; i < 4; ++i) a[i] = At[ty * 4 + i][k0 + kk];
      float4 b0 = *(const float4*)&Ws[kk][tx * 4];
      float bb0[4] = {b0.x, b0.y, b0.z, b0.w};
#pragma unroll
      for (int i = 0; i < 4; ++i)
#pragma unroll
        for (int j = 0; j < 4; ++j) accA[i][j] = fmaf(a[i], bb0[j], accA[i][j]);
      if (NOUT == 256) {
        float4 b1 = *(const float4*)&Ws[kk][128 + tx * 4];
        float bb1[4] = {b1.x, b1.y, b1.z, b1.w};
#pragma unroll
        for (int i = 0; i < 4; ++i)
#pragma unroll
          for (int j = 0; j < 4; ++j) accB[i][j] = fmaf(a[i], bb1[j], accB[i][j]);
      }
    }
    __syncthreads();
  }

#pragma unroll
  for (int i = 0; i < 4; ++i) {
    int row = blk + ty * 4 + i;
    if (row < n) {
      float4 o;
      o.x = accA[i][0]; o.y = accA[i][1]; o.z = accA[i][2]; o.w = accA[i][3];
      *(float4*)(Hn + (size_t)row * NOUT + tx * 4) = o;
      if (NOUT == 256) {
        float4 p;
        p.x = accB[i][0]; p.y = accB[i][1]; p.z = accB[i][2]; p.w = accB[i][3];
        *(float4*)(Hn + (size_t)row * NOUT + 128 + tx * 4) = p;
      }
    }
  }
}

// ---------------- final aggregation (layer 6): out = agg + b, no lrelu ----------------

template <int COLS>
__global__ __launch_bounds__(256) void aggregate_kernel(
    const float* __restrict__ H, const int* __restrict__ rowptr,
    const int* __restrict__ esrc, const float* __restrict__ ew,
    const float* __restrict__ dinv, const float* __restrict__ bias,
    float* __restrict__ out, int n) {
  const int lane = threadIdx.x & 63;
  const int node = blockIdx.x * 4 + (threadIdx.x >> 6);
  if (node >= n) return;
  constexpr int V = COLS / 64;
  const float di = dinv[node];
  float acc[V];
  if constexpr (V == 4) {
    float4 h = *(const float4*)(H + (size_t)node * COLS + lane * 4);
    acc[0] = di * h.x; acc[1] = di * h.y; acc[2] = di * h.z; acc[3] = di * h.w;
  } else {
    float2 h = *(const float2*)(H + (size_t)node * COLS + lane * 2);
    acc[0] = di * h.x; acc[1] = di * h.y;
  }
  const int e1 = rowptr[node + 1];
  int e = rowptr[node];
  for (; e + 4 <= e1; e += 4) {
    int s0 = esrc[e + 0], s1 = esrc[e + 1], s2 = esrc[e + 2], s3 = esrc[e + 3];
    float w0 = ew[e + 0], w1 = ew[e + 1], w2 = ew[e + 2], w3 = ew[e + 3];
    if constexpr (V == 4) {
      float4 h0 = *(const float4*)(H + (size_t)s0 * COLS + lane * 4);
      float4 h1 = *(const float4*)(H + (size_t)s1 * COLS + lane * 4);
      float4 h2 = *(const float4*)(H + (size_t)s2 * COLS + lane * 4);
      float4 h3 = *(const float4*)(H + (size_t)s3 * COLS + lane * 4);
      acc[0] = fmaf(w3, h3.x, fmaf(w2, h2.x, fmaf(w1, h1.x, fmaf(w0, h0.x, acc[0]))));
      acc[1] = fmaf(w3, h3.y, fmaf(w2, h2.y, fmaf(w1, h1.y, fmaf(w0, h0.y, acc[1]))));
      acc[2] = fmaf(w3, h3.z, fmaf(w2, h2.z, fmaf(w1, h1.z, fmaf(w0, h0.z, acc[2]))));
      acc[3] = fmaf(w3, h3.w, fmaf(w2, h2.w, fmaf(w1, h1.w, fmaf(w0, h0.w, acc[3]))));
    } else {
      float2 h0 = *(const float2*)(H + (size_t)s0 * COLS + lane * 2);
      float2 h1 = *(const float2*)(H + (size_t)s1 * COLS + lane * 2);
      float2 h2 = *(const float2*)(H + (size_t)s2 * COLS + lane * 2);
      float2 h3 = *(const float2*)(H + (size_t)s3 * COLS + lane * 2);
      acc[0] = fmaf(w3, h3.x, fmaf(w2, h2.x, fmaf(w1, h1.x, fmaf(w0, h0.x, acc[0]))));
      acc[1] = fmaf(w3, h3.y, fmaf(w2, h2.y, fmaf(w1, h1.y, fmaf(w0, h0.y, acc[1]))));
    }
  }
  for (; e < e1; ++e) {
    int s = esrc[e];
    float w = ew[e];
    if constexpr (V == 4) {
      float4 h = *(const float4*)(H + (size_t)s * COLS + lane * 4);
      acc[0] = fmaf(w, h.x, acc[0]);
      acc[1] = fmaf(w, h.y, acc[1]);
      acc[2] = fmaf(w, h.z, acc[2]);
      acc[3] = fmaf(w, h.w, acc[3]);
    } else {
      float2 h = *(const float2*)(H + (size_t)s * COLS + lane * 2);
      acc[0] = fmaf(w, h.x, acc[0]);
      acc[1] = fmaf(w, h.y, acc[1]);
    }
  }
  if constexpr (V == 4) {
    float4 b = *(const float4*)(bias + lane * 4);
    float4 o;
    o.x = fmaf(di, acc[0], b.x);
    o.y = fmaf(di, acc[1], b.y);
    o.z = fmaf(di, acc[2], b.z);
    o.w = fmaf(di, acc[3], b.w);
    *(float4*)(out + (size_t)node * COLS + lane * 4) = o;
  } else {
    float2 b = *(const float2*)(bias + lane * 2);
    float2 o;
    o.x = fmaf(di, acc[0], b.x);
    o.y = fmaf(di, acc[1], b.y);
    *(float2*)(out + (size_t)node * COLS + lane * 2) = o;
  }
}

// ---------------- launch ----------------

extern "C" void kernel_launch(void* const* d_in, const int* in_sizes, int n_in,
                              void* d_out, int out_size, void* d_ws, size_t ws_size,
                              hipStream_t stream) {
  (void)n_in; (void)out_size; (void)ws_size;
  const float* x = (const float*)d_in[0];
  const int N = in_sizes[0] / 256;
  const int* ei = (const int*)d_in[1];
  const int E = in_sizes[1] / 2;
  const int* srcp = ei;
  const int* dstp = ei + E;
  const float* Wl[6];
  const float* Bl[6];
  for (int i = 0; i < 6; i++) {
    Wl[i] = (const float*)d_in[2 + 2 * i];
    Bl[i] = (const float*)d_in[3 + 2 * i];
  }
  float* out = (float*)d_out;

  char* p = (char*)d_ws;
  auto carve = [&](size_t bytes) {
    char* r = p;
    p += (bytes + 255) & ~(size_t)255;
    return (void*)r;
  };
  float* bufA = (float*)carve((size_t)N * 256 * 4);
  float* bufB = (float*)carve((size_t)N * 256 * 4);
  int* cnt = (int*)carve((size_t)N * 4);
  float* dinv = (float*)carve((size_t)N * 4);
  int* incl = (int*)carve((size_t)N * 4);
  int* rowptr = (int*)carve((size_t)(N + 1) * 4);
  int* esrc = (int*)carve((size_t)E * 4);
  float* ew = (float*)carve((size_t)E * 4);
  int* bsum = (int*)carve(1024);
  int* boff = (int*)carve(1024);

  const int NB = (N + 255) / 256;

  hipMemsetAsync(cnt, 0, (size_t)N * 4, stream);
  hist_kernel<<<(E + 255) / 256, 256, 0, stream>>>(dstp, cnt, E);
  dinv_kernel<<<NB, 256, 0, stream>>>(cnt, dinv, N);
  scan1_kernel<<<NB, 256, 0, stream>>>(cnt, incl, bsum, N);
  scan2_kernel<<<1, 256, 0, stream>>>(bsum, boff, NB);
  scan3_kernel<<<NB, 256, 0, stream>>>(incl, boff, rowptr, N);
  hipMemsetAsync(cnt, 0, (size_t)N * 4, stream);
  scatter_kernel<<<(E + 255) / 256, 256, 0, stream>>>(srcp, dstp, rowptr, cnt, dinv,
                                                      esrc, ew, E);

  const int gm = (N + 127) / 128;
  const int gfuse = (N + 31) / 32;
  const int gagg = (N + 3) / 4;

  // layer 1 GEMM: H1 = x @ W1^T  -> bufB
  gemm_kernel<false, 256><<<dim3(gm, 2), 256, 0, stream>>>(x, Wl[0], bufB, N);
  // fused layers: H_{l+1} = lrelu(agg_l(H_l)+b_l) @ W_{l+1}^T
  fused_agg_gemm<256><<<gfuse, 256, 0, stream>>>(bufB, rowptr, esrc, ew, dinv, Bl[0], Wl[1], bufA, N);
  fused_agg_gemm<256><<<gfuse, 256, 0, stream>>>(bufA, rowptr, esrc, ew, dinv, Bl[1], Wl[2], bufB, N);
  fused_agg_gemm<256><<<gfuse, 256, 0, stream>>>(bufB, rowptr, esrc, ew, dinv, Bl[2], Wl[3], bufA, N);
  fused_agg_gemm<256><<<gfuse, 256, 0, stream>>>(bufA, rowptr, esrc, ew, dinv, Bl[3], Wl[4], bufB, N);
  fused_agg_gemm<128><<<gfuse, 256, 0, stream>>>(bufB, rowptr, esrc, ew, dinv, Bl[4], Wl[5], bufA, N);
  // final aggregation (layer 6): out = agg(H6) + b6
  aggregate_kernel<128><<<gagg, 256, 0, stream>>>(bufA, rowptr, esrc, ew, dinv, Bl[5], out, N);
}